// Round 4
// baseline (996.549 us; speedup 1.0000x reference)
//
#include <hip/hip_runtime.h>

// ESMProjectionHead — f32 inputs, f32 output. B=64, L=4096, D=128, RL=64, RD=16, DOUT=512
// detect: decide mask layout (byte-bool vs int32-bool) from the data itself.
// k1 (memory-bound, f32 VALU): per (b, 256-row L-chunk) block, 4 tiles of 64 rows:
//   Y[64,16] = X_tile @ Bc ; mask rows ; U[64,16] += A_tile^T @ Y  -> atomicAdd f32
// k2a: z[64,512] = U[64,1024] @ Hc
// k2b: h = z@W1+b1 -> LN -> ReLU -> out = h@W2+b2 (f32 store)

// ---------------- mask-layout detection -----------------------------------
// Scan first 65536 u32 words (= 256 KB, the full buffer if byte-packed, the
// first quarter if int32). Any word value > 1 => byte-packed bools.
__global__ __launch_bounds__(256) void detect_mask(
    const unsigned int* __restrict__ m, int* __restrict__ flag)
{
    unsigned int v = 0;
    int base = (blockIdx.x * 256 + threadIdx.x) * 4;
#pragma unroll
    for (int i = 0; i < 4; ++i) v |= m[base + i];
    unsigned long long any = __ballot(v > 1u);
    if ((threadIdx.x & 63) == 0 && any) atomicOr(flag, 1);
}

// ---------------- Kernel 1: low-rank projections (f32) --------------------
#define XS_STRIDE 132   // 128 + 4: float4-aligned, rotates banks
#define YS_STRIDE 20
__global__ __launch_bounds__(256, 2) void k1_proj(
    const float* __restrict__ emb,          // [64,4096,128]
    const void* __restrict__ maskp,         // [64,4096] bool (byte or int32)
    const float* __restrict__ Bc,           // [128,16]
    const float* __restrict__ Ac,           // [4096,64]
    float* __restrict__ Uws,                // [64,64,16] f32, pre-zeroed
    const int* __restrict__ flag)
{
    __shared__ __align__(16) float Xs[64 * XS_STRIDE];
    __shared__ __align__(16) float As[64 * 64];
    __shared__ __align__(16) float Ys[64 * YS_STRIDE];
    __shared__ __align__(16) float BcS[128 * 16];

    const int tid  = threadIdx.x;
    const int lane = tid & 63;
    const int wave = tid >> 6;
    const int b    = blockIdx.x >> 4;
    const int c    = blockIdx.x & 15;       // 256-row chunk
    const int byte_mode = *flag;            // wave-uniform

    // stage Bc once (2048 floats)
#pragma unroll
    for (int i = 0; i < 8; ++i)
        BcS[i * 256 + tid] = Bc[i * 256 + tid];

    float accU[4] = {0.f, 0.f, 0.f, 0.f};   // U[k=lane][wave*4 .. +3]

    for (int t = 0; t < 4; ++t) {
        const long l0 = (long)c * 256 + t * 64;
        const float* xsrc = emb + ((long)b * 4096 + l0) * 128;
        const float* asrc = Ac + l0 * 64;

        // stage X tile 64x128 (pad stride 132): 8 x float4 per thread
#pragma unroll
        for (int i = 0; i < 8; ++i) {
            int e = (i * 256 + tid) * 4;
            int r = e >> 7, k = e & 127;
            float4 v = *(const float4*)(xsrc + e);
            *(float4*)(Xs + r * XS_STRIDE + k) = v;
        }
        // stage A tile 64x64: 4 x float4 per thread (linear)
#pragma unroll
        for (int i = 0; i < 4; ++i) {
            int e = (i * 256 + tid) * 4;
            *(float4*)(As + e) = *(const float4*)(asrc + e);
        }
        __syncthreads();

        // ---- Y: thread computes row l=lane, cols wave*4..+3 ----
        float ya0 = 0.f, ya1 = 0.f, ya2 = 0.f, ya3 = 0.f;
        const float* xr = Xs + lane * XS_STRIDE;
        const float* bp = BcS + wave * 4;
        for (int k4 = 0; k4 < 128; k4 += 4) {
            float4 xv = *(const float4*)(xr + k4);
#pragma unroll
            for (int i = 0; i < 4; ++i) {
                float4 bv = *(const float4*)(bp + (k4 + i) * 16);  // wave-uniform
                float x = (i == 0) ? xv.x : (i == 1) ? xv.y : (i == 2) ? xv.z : xv.w;
                ya0 += x * bv.x; ya1 += x * bv.y; ya2 += x * bv.z; ya3 += x * bv.w;
            }
        }
        long midx = (long)b * 4096 + l0 + lane;
        bool mb = byte_mode ? (((const unsigned char*)maskp)[midx] != 0)
                            : (((const int*)maskp)[midx] != 0);
        float mv = mb ? 1.f : 0.f;
        float4 yo = {ya0 * mv, ya1 * mv, ya2 * mv, ya3 * mv};
        *(float4*)(Ys + lane * YS_STRIDE + wave * 4) = yo;
        __syncthreads();

        // ---- U += A^T @ Y: thread owns k=lane, cols wave*4..+3, sum over l ----
        for (int l = 0; l < 64; ++l) {
            float av = As[l * 64 + lane];                             // conflict-free
            float4 yv = *(const float4*)(Ys + l * YS_STRIDE + wave * 4);  // broadcast
            accU[0] += av * yv.x; accU[1] += av * yv.y;
            accU[2] += av * yv.z; accU[3] += av * yv.w;
        }
        __syncthreads();
    }

    float* ub = Uws + (long)b * 1024 + lane * 16 + wave * 4;
#pragma unroll
    for (int i = 0; i < 4; ++i)
        atomicAdd(ub + i, accU[i]);
}

// ---------------- Kernel 2a: z = U @ Hc (f32) -----------------------------
__global__ __launch_bounds__(256) void k2a_z(
    const float* __restrict__ Uws,          // [64,1024]
    const float* __restrict__ Hc,           // [1024,512]
    float* __restrict__ zws)                // [64,512]
{
    __shared__ __align__(16) float Us[4 * 1024];

    const int tid = threadIdx.x;
    const int mt  = blockIdx.x >> 3;        // 16 row-groups of 4
    const int nt  = blockIdx.x & 7;         // 8 col-groups of 64

#pragma unroll
    for (int i = 0; i < 16; ++i)
        Us[i * 256 + tid] = Uws[(long)mt * 4 * 1024 + i * 256 + tid];
    __syncthreads();

    const int r  = tid >> 6;                // 0..3 (wave-uniform)
    const int cg = nt * 64 + (tid & 63);
    const float* ur = Us + r * 1024;
    float acc = 0.f;
    for (int k = 0; k < 1024; k += 4) {
        float4 uv = *(const float4*)(ur + k);
        acc += uv.x * Hc[(k + 0) * 512 + cg];
        acc += uv.y * Hc[(k + 1) * 512 + cg];
        acc += uv.z * Hc[(k + 2) * 512 + cg];
        acc += uv.w * Hc[(k + 3) * 512 + cg];
    }
    zws[((long)mt * 4 + r) * 512 + cg] = acc;
}

// ---------------- Kernel 2b: expander head (f32 -> f32) -------------------
__global__ __launch_bounds__(256) void k2b_head(
    const float* __restrict__ zws,          // [64,512]
    const float* __restrict__ W1,           // [512,512]
    const float* __restrict__ b1,
    const float* __restrict__ lnw,
    const float* __restrict__ lnb,
    const float* __restrict__ W2,
    const float* __restrict__ b2,
    float* __restrict__ out)                // [64,512] f32
{
    __shared__ __align__(16) float zs[512];
    __shared__ __align__(16) float hs[512];
    __shared__ float red[8];

    const int tid  = threadIdx.x;
    const int lane = tid & 63;
    const int wave = tid >> 6;
    const int b    = blockIdx.x;

    zs[tid] = zws[(long)b * 512 + tid];
    zs[tid + 256] = zws[(long)b * 512 + tid + 256];
    __syncthreads();

    float h0 = b1[tid], h1 = b1[tid + 256];
    for (int k = 0; k < 512; k += 4) {
        float4 zv = *(const float4*)(zs + k);   // block-uniform broadcast
        h0 += zv.x * W1[(k + 0) * 512 + tid];
        h0 += zv.y * W1[(k + 1) * 512 + tid];
        h0 += zv.z * W1[(k + 2) * 512 + tid];
        h0 += zv.w * W1[(k + 3) * 512 + tid];
        h1 += zv.x * W1[(k + 0) * 512 + tid + 256];
        h1 += zv.y * W1[(k + 1) * 512 + tid + 256];
        h1 += zv.z * W1[(k + 2) * 512 + tid + 256];
        h1 += zv.w * W1[(k + 3) * 512 + tid + 256];
    }

    float s = h0 + h1, s2 = h0 * h0 + h1 * h1;
#pragma unroll
    for (int m = 32; m >= 1; m >>= 1) {
        s  += __shfl_xor(s, m);
        s2 += __shfl_xor(s2, m);
    }
    if (lane == 0) { red[wave] = s; red[wave + 4] = s2; }
    __syncthreads();
    float ts  = red[0] + red[1] + red[2] + red[3];
    float ts2 = red[4] + red[5] + red[6] + red[7];
    float mu   = ts * (1.f / 512.f);
    float var  = ts2 * (1.f / 512.f) - mu * mu;
    float rstd = rsqrtf(var + 1e-5f);

    float g0 = (h0 - mu) * rstd * lnw[tid] + lnb[tid];
    float g1 = (h1 - mu) * rstd * lnw[tid + 256] + lnb[tid + 256];
    hs[tid] = g0 > 0.f ? g0 : 0.f;
    hs[tid + 256] = g1 > 0.f ? g1 : 0.f;
    __syncthreads();

    float o0 = b2[tid], o1 = b2[tid + 256];
    for (int k = 0; k < 512; k += 4) {
        float4 hv = *(const float4*)(hs + k);
        o0 += hv.x * W2[(k + 0) * 512 + tid];
        o0 += hv.y * W2[(k + 1) * 512 + tid];
        o0 += hv.z * W2[(k + 2) * 512 + tid];
        o0 += hv.w * W2[(k + 3) * 512 + tid];
        o1 += hv.x * W2[(k + 0) * 512 + tid + 256];
        o1 += hv.y * W2[(k + 1) * 512 + tid + 256];
        o1 += hv.z * W2[(k + 2) * 512 + tid + 256];
        o1 += hv.w * W2[(k + 3) * 512 + tid + 256];
    }
    out[(long)b * 512 + tid] = o0;
    out[(long)b * 512 + tid + 256] = o1;
}

extern "C" void kernel_launch(void* const* d_in, const int* in_sizes, int n_in,
                              void* d_out, int out_size, void* d_ws, size_t ws_size,
                              hipStream_t stream) {
    const float* emb = (const float*)d_in[0];
    const void*  msk = (const void*)d_in[1];
    const float* Bc  = (const float*)d_in[2];
    const float* Ac  = (const float*)d_in[3];
    const float* Hc  = (const float*)d_in[4];
    const float* W1  = (const float*)d_in[5];
    const float* b1  = (const float*)d_in[6];
    const float* lnw = (const float*)d_in[7];
    const float* lnb = (const float*)d_in[8];
    const float* W2  = (const float*)d_in[9];
    const float* b2  = (const float*)d_in[10];

    float* Uws = (float*)d_ws;                            // 256 KB
    float* zws = (float*)((char*)d_ws + 64 * 1024 * 4);   // 128 KB
    int*   flg = (int*)((char*)d_ws + (64 * 1024 + 64 * 512) * 4);

    hipMemsetAsync(Uws, 0, 64 * 1024 * 4, stream);
    hipMemsetAsync(flg, 0, 4, stream);
    detect_mask<<<64, 256, 0, stream>>>((const unsigned int*)msk, flg);
    k1_proj<<<1024, 256, 0, stream>>>(emb, msk, Bc, Ac, Uws, flg);
    k2a_z<<<128, 256, 0, stream>>>(Uws, Hc, zws);
    k2b_head<<<64, 256, 0, stream>>>(zws, W1, b1, lnw, lnb, W2, b2,
                                     (float*)d_out);
}

// Round 5
// 971.768 us; speedup vs baseline: 1.0255x; 1.0255x over previous
//
#include <hip/hip_runtime.h>

// ESMProjectionHead — f32 inputs, f32 output. B=64, L=4096, D=128, RL=64, RD=16, DOUT=512
// detect: decide mask layout (byte-bool vs int32-bool) from the data itself.
// k1: per (b, 256-row L-chunk) block: Y = X_tile @ Bc ; mask rows ;
//     U_partial += A_tile^T @ Y ; plain-store partial to Part[c][b]  (NO atomics —
//     fp32 global atomicAdd is a CAS loop on gfx950 => 1.7 GB TCC write storm in R4)
// k2a: z[64,512] = (sum_c Part[c]) @ Hc
// k2b: h = z@W1+b1 -> LN -> ReLU -> out = h@W2+b2 (f32 store)

// ---------------- mask-layout detection -----------------------------------
__global__ __launch_bounds__(256) void detect_mask(
    const unsigned int* __restrict__ m, int* __restrict__ flag)
{
    unsigned int v = 0;
    int base = (blockIdx.x * 256 + threadIdx.x) * 4;
#pragma unroll
    for (int i = 0; i < 4; ++i) v |= m[base + i];
    unsigned long long any = __ballot(v > 1u);
    if ((threadIdx.x & 63) == 0 && any) atomicOr(flag, 1);
}

// ---------------- Kernel 1: low-rank projections (f32) --------------------
#define XS_STRIDE 132   // 128 + 4: float4-aligned, rotates banks
#define YS_STRIDE 20
__global__ __launch_bounds__(256, 2) void k1_proj(
    const float* __restrict__ emb,          // [64,4096,128]
    const void* __restrict__ maskp,         // [64,4096] bool (byte or int32)
    const float* __restrict__ Bc,           // [128,16]
    const float* __restrict__ Ac,           // [4096,64]
    float* __restrict__ Part,               // [16][64][1024] f32 partials
    const int* __restrict__ flag)
{
    __shared__ __align__(16) float Xs[64 * XS_STRIDE];
    __shared__ __align__(16) float As[64 * 64];
    __shared__ __align__(16) float Ys[64 * YS_STRIDE];
    __shared__ __align__(16) float BcS[128 * 16];

    const int tid  = threadIdx.x;
    const int lane = tid & 63;
    const int wave = tid >> 6;
    const int b    = blockIdx.x >> 4;
    const int c    = blockIdx.x & 15;       // 256-row chunk
    const int byte_mode = *flag;            // block-uniform

    // stage Bc once (2048 floats)
#pragma unroll
    for (int i = 0; i < 8; ++i)
        BcS[i * 256 + tid] = Bc[i * 256 + tid];

    float accU[4] = {0.f, 0.f, 0.f, 0.f};   // U[k=lane][wave*4 .. +3]

    for (int t = 0; t < 4; ++t) {
        const long l0 = (long)c * 256 + t * 64;
        const float* xsrc = emb + ((long)b * 4096 + l0) * 128;
        const float* asrc = Ac + l0 * 64;

        // stage X tile 64x128 (pad stride 132): 8 x float4 per thread
#pragma unroll
        for (int i = 0; i < 8; ++i) {
            int e = (i * 256 + tid) * 4;
            int r = e >> 7, k = e & 127;
            float4 v = *(const float4*)(xsrc + e);
            *(float4*)(Xs + r * XS_STRIDE + k) = v;
        }
        // stage A tile 64x64: 4 x float4 per thread (linear)
#pragma unroll
        for (int i = 0; i < 4; ++i) {
            int e = (i * 256 + tid) * 4;
            *(float4*)(As + e) = *(const float4*)(asrc + e);
        }
        __syncthreads();

        // ---- Y: thread computes row l=lane, cols wave*4..+3 ----
        float ya0 = 0.f, ya1 = 0.f, ya2 = 0.f, ya3 = 0.f;
        const float* xr = Xs + lane * XS_STRIDE;
        const float* bp = BcS + wave * 4;
        for (int k4 = 0; k4 < 128; k4 += 4) {
            float4 xv = *(const float4*)(xr + k4);
#pragma unroll
            for (int i = 0; i < 4; ++i) {
                float4 bv = *(const float4*)(bp + (k4 + i) * 16);  // uniform bcast
                float x = (i == 0) ? xv.x : (i == 1) ? xv.y : (i == 2) ? xv.z : xv.w;
                ya0 += x * bv.x; ya1 += x * bv.y; ya2 += x * bv.z; ya3 += x * bv.w;
            }
        }
        long midx = (long)b * 4096 + l0 + lane;
        bool mb = byte_mode ? (((const unsigned char*)maskp)[midx] != 0)
                            : (((const int*)maskp)[midx] != 0);
        float mv = mb ? 1.f : 0.f;
        float4 yo = {ya0 * mv, ya1 * mv, ya2 * mv, ya3 * mv};
        *(float4*)(Ys + lane * YS_STRIDE + wave * 4) = yo;
        __syncthreads();

        // ---- U += A^T @ Y: thread owns k=lane, cols wave*4..+3, sum over l ----
        for (int l = 0; l < 64; ++l) {
            float av = As[l * 64 + lane];                                // conflict-free
            float4 yv = *(const float4*)(Ys + l * YS_STRIDE + wave * 4); // bcast
            accU[0] += av * yv.x; accU[1] += av * yv.y;
            accU[2] += av * yv.z; accU[3] += av * yv.w;
        }
        __syncthreads();
    }

    // plain store of this block's private partial (4 KB, no atomics)
    float4 uo = {accU[0], accU[1], accU[2], accU[3]};
    *(float4*)(Part + ((long)(c * 64 + b)) * 1024 + lane * 16 + wave * 4) = uo;
}

// ---------------- Kernel 2a: z = (sum_c Part) @ Hc (f32) ------------------
__global__ __launch_bounds__(256) void k2a_z(
    const float* __restrict__ Part,         // [16][64][1024]
    const float* __restrict__ Hc,           // [1024,512]
    float* __restrict__ zws)                // [64,512]
{
    __shared__ __align__(16) float Us[4 * 1024];

    const int tid = threadIdx.x;
    const int mt  = blockIdx.x >> 3;        // 16 row-groups of 4
    const int nt  = blockIdx.x & 7;         // 8 col-groups of 64

    // stage 4 U rows, reducing the 16 partials
#pragma unroll
    for (int i = 0; i < 16; ++i) {
        int flat = i * 256 + tid;           // [0,4096)
        int brow = flat >> 10;              // 0..3
        int col  = flat & 1023;
        float s = 0.f;
#pragma unroll
        for (int cc = 0; cc < 16; ++cc)
            s += Part[((long)(cc * 64 + mt * 4 + brow)) * 1024 + col];
        Us[flat] = s;
    }
    __syncthreads();

    const int r  = tid >> 6;                // 0..3 (wave-uniform)
    const int cg = nt * 64 + (tid & 63);
    const float* ur = Us + r * 1024;
    float acc = 0.f;
    for (int k = 0; k < 1024; k += 4) {
        float4 uv = *(const float4*)(ur + k);
        acc += uv.x * Hc[(k + 0) * 512 + cg];
        acc += uv.y * Hc[(k + 1) * 512 + cg];
        acc += uv.z * Hc[(k + 2) * 512 + cg];
        acc += uv.w * Hc[(k + 3) * 512 + cg];
    }
    zws[((long)mt * 4 + r) * 512 + cg] = acc;
}

// ---------------- Kernel 2b: expander head (f32 -> f32) -------------------
__global__ __launch_bounds__(256) void k2b_head(
    const float* __restrict__ zws,          // [64,512]
    const float* __restrict__ W1,           // [512,512]
    const float* __restrict__ b1,
    const float* __restrict__ lnw,
    const float* __restrict__ lnb,
    const float* __restrict__ W2,
    const float* __restrict__ b2,
    float* __restrict__ out)                // [64,512] f32
{
    __shared__ __align__(16) float zs[512];
    __shared__ __align__(16) float hs[512];
    __shared__ float red[8];

    const int tid  = threadIdx.x;
    const int lane = tid & 63;
    const int wave = tid >> 6;
    const int b    = blockIdx.x;

    zs[tid] = zws[(long)b * 512 + tid];
    zs[tid + 256] = zws[(long)b * 512 + tid + 256];
    __syncthreads();

    float h0 = b1[tid], h1 = b1[tid + 256];
    for (int k = 0; k < 512; k += 4) {
        float4 zv = *(const float4*)(zs + k);   // block-uniform broadcast
        h0 += zv.x * W1[(k + 0) * 512 + tid];
        h0 += zv.y * W1[(k + 1) * 512 + tid];
        h0 += zv.z * W1[(k + 2) * 512 + tid];
        h0 += zv.w * W1[(k + 3) * 512 + tid];
        h1 += zv.x * W1[(k + 0) * 512 + tid + 256];
        h1 += zv.y * W1[(k + 1) * 512 + tid + 256];
        h1 += zv.z * W1[(k + 2) * 512 + tid + 256];
        h1 += zv.w * W1[(k + 3) * 512 + tid + 256];
    }

    float s = h0 + h1, s2 = h0 * h0 + h1 * h1;
#pragma unroll
    for (int m = 32; m >= 1; m >>= 1) {
        s  += __shfl_xor(s, m);
        s2 += __shfl_xor(s2, m);
    }
    if (lane == 0) { red[wave] = s; red[wave + 4] = s2; }
    __syncthreads();
    float ts  = red[0] + red[1] + red[2] + red[3];
    float ts2 = red[4] + red[5] + red[6] + red[7];
    float mu   = ts * (1.f / 512.f);
    float var  = ts2 * (1.f / 512.f) - mu * mu;
    float rstd = rsqrtf(var + 1e-5f);

    float g0 = (h0 - mu) * rstd * lnw[tid] + lnb[tid];
    float g1 = (h1 - mu) * rstd * lnw[tid + 256] + lnb[tid + 256];
    hs[tid] = g0 > 0.f ? g0 : 0.f;
    hs[tid + 256] = g1 > 0.f ? g1 : 0.f;
    __syncthreads();

    float o0 = b2[tid], o1 = b2[tid + 256];
    for (int k = 0; k < 512; k += 4) {
        float4 hv = *(const float4*)(hs + k);
        o0 += hv.x * W2[(k + 0) * 512 + tid];
        o0 += hv.y * W2[(k + 1) * 512 + tid];
        o0 += hv.z * W2[(k + 2) * 512 + tid];
        o0 += hv.w * W2[(k + 3) * 512 + tid];
        o1 += hv.x * W2[(k + 0) * 512 + tid + 256];
        o1 += hv.y * W2[(k + 1) * 512 + tid + 256];
        o1 += hv.z * W2[(k + 2) * 512 + tid + 256];
        o1 += hv.w * W2[(k + 3) * 512 + tid + 256];
    }
    out[(long)b * 512 + tid] = o0;
    out[(long)b * 512 + tid + 256] = o1;
}

extern "C" void kernel_launch(void* const* d_in, const int* in_sizes, int n_in,
                              void* d_out, int out_size, void* d_ws, size_t ws_size,
                              hipStream_t stream) {
    const float* emb = (const float*)d_in[0];
    const void*  msk = (const void*)d_in[1];
    const float* Bc  = (const float*)d_in[2];
    const float* Ac  = (const float*)d_in[3];
    const float* Hc  = (const float*)d_in[4];
    const float* W1  = (const float*)d_in[5];
    const float* b1  = (const float*)d_in[6];
    const float* lnw = (const float*)d_in[7];
    const float* lnb = (const float*)d_in[8];
    const float* W2  = (const float*)d_in[9];
    const float* b2  = (const float*)d_in[10];

    float* Part = (float*)d_ws;                              // 16*64*1024*4 = 4 MB
    float* zws  = (float*)((char*)d_ws + 16 * 64 * 1024 * 4); // 128 KB
    int*   flg  = (int*)((char*)d_ws + 16 * 64 * 1024 * 4 + 64 * 512 * 4);

    hipMemsetAsync(flg, 0, 4, stream);
    detect_mask<<<64, 256, 0, stream>>>((const unsigned int*)msk, flg);
    k1_proj<<<1024, 256, 0, stream>>>(emb, msk, Bc, Ac, Part, flg);
    k2a_z<<<128, 256, 0, stream>>>(Part, Hc, zws);
    k2b_head<<<64, 256, 0, stream>>>(zws, W1, b1, lnw, lnb, W2, b2,
                                     (float*)d_out);
}

// Round 6
// 335.764 us; speedup vs baseline: 2.9680x; 2.8942x over previous
//
#include <hip/hip_runtime.h>

// ESMProjectionHead — f32 in, f32 out. B=64, L=4096, D=128, RL=64, RD=16, DOUT=512
// R6: k1 without X-LDS-staging. Thread (r=tid>>2, q=tid&3): 32 X floats in regs,
// y[16] FMA vs LDS-broadcast Bc, shfl_xor quarter-reduce, mask, Ys -> LDS.
// U-loop (k=lane, cols wave*4..+3) unchanged from verified R5. No atomics.
// LDS 29 KB (was 62), 2 barriers/tile (was 3), occupancy ~50% (was 17%).

// ---------------- mask-layout detection -----------------------------------
__global__ __launch_bounds__(256) void detect_mask(
    const unsigned int* __restrict__ m, int* __restrict__ flag)
{
    unsigned int v = 0;
    int base = (blockIdx.x * 256 + threadIdx.x) * 4;
#pragma unroll
    for (int i = 0; i < 4; ++i) v |= m[base + i];
    unsigned long long any = __ballot(v > 1u);
    if ((threadIdx.x & 63) == 0 && any) atomicOr(flag, 1);
}

// ---------------- Kernel 1: low-rank projections (f32) --------------------
#define YS_STRIDE 20
__global__ __launch_bounds__(256, 4) void k1_proj(
    const float* __restrict__ emb,          // [64,4096,128]
    const void* __restrict__ maskp,         // [64,4096] bool (byte or int32)
    const float* __restrict__ Bc,           // [128,16]
    const float* __restrict__ Ac,           // [4096,64]
    float* __restrict__ Part,               // [16][64][1024] f32 partials
    const int* __restrict__ flag)
{
    __shared__ __align__(16) float BcS[128 * 16];       // 8 KB
    __shared__ __align__(16) float As[64 * 64];         // 16 KB
    __shared__ __align__(16) float Ys[64 * YS_STRIDE];  // 5.1 KB

    const int tid  = threadIdx.x;
    const int lane = tid & 63;
    const int wave = tid >> 6;
    const int q    = tid & 3;               // K-quarter (32 ks)
    const int r    = tid >> 2;              // row within 64-row sub-tile
    const int b    = blockIdx.x >> 4;
    const int c    = blockIdx.x & 15;       // 256-row chunk
    const int byte_mode = *flag;            // block-uniform

    // stage Bc once
#pragma unroll
    for (int i = 0; i < 8; ++i)
        BcS[i * 256 + tid] = Bc[i * 256 + tid];
    __syncthreads();

    float accU[4] = {0.f, 0.f, 0.f, 0.f};   // U[k=lane][wave*4 .. +3]

    for (int t = 0; t < 4; ++t) {
        const long l0 = (long)c * 256 + t * 64;
        const float* asrc = Ac + l0 * 64;

        // stage A tile 64x64 (16 KB): 4 x float4 per thread (no dependency on Y)
#pragma unroll
        for (int i = 0; i < 4; ++i) {
            int e = (i * 256 + tid) * 4;
            *(float4*)(As + e) = *(const float4*)(asrc + e);
        }

        // ---- X straight to registers: row r, ks q*32..q*32+31 ----
        const float* xrow = emb + ((long)b * 4096 + l0 + r) * 128 + q * 32;
        float4 xv[8];
#pragma unroll
        for (int j = 0; j < 8; ++j) xv[j] = *(const float4*)(xrow + j * 4);

        // ---- y[16] = sum_k x[k] * Bc[k][:] over this thread's 32 ks ----
        float y[16];
#pragma unroll
        for (int j = 0; j < 16; ++j) y[j] = 0.f;
#pragma unroll
        for (int j4 = 0; j4 < 8; ++j4) {
            float4 v = xv[j4];
#pragma unroll
            for (int i = 0; i < 4; ++i) {
                int k = q * 32 + j4 * 4 + i;
                float x = (i == 0) ? v.x : (i == 1) ? v.y : (i == 2) ? v.z : v.w;
#pragma unroll
                for (int c4 = 0; c4 < 4; ++c4) {
                    float4 bv = *(const float4*)(BcS + k * 16 + c4 * 4); // 4-addr bcast
                    y[c4 * 4 + 0] += x * bv.x;
                    y[c4 * 4 + 1] += x * bv.y;
                    y[c4 * 4 + 2] += x * bv.z;
                    y[c4 * 4 + 3] += x * bv.w;
                }
            }
        }
        // reduce the 4 K-quarters (lanes differing in bits 0-1), register-only
#pragma unroll
        for (int j = 0; j < 16; ++j) {
            y[j] += __shfl_xor(y[j], 1);
            y[j] += __shfl_xor(y[j], 2);
        }

        // mask row, write this thread's quarter of columns (static indexing)
        long midx = (long)b * 4096 + l0 + r;
        bool mb = byte_mode ? (((const unsigned char*)maskp)[midx] != 0)
                            : (((const int*)maskp)[midx] != 0);
        float mv = mb ? 1.f : 0.f;
        float4 yo;
        if (q == 0)      yo = make_float4(y[0],  y[1],  y[2],  y[3]);
        else if (q == 1) yo = make_float4(y[4],  y[5],  y[6],  y[7]);
        else if (q == 2) yo = make_float4(y[8],  y[9],  y[10], y[11]);
        else             yo = make_float4(y[12], y[13], y[14], y[15]);
        yo.x *= mv; yo.y *= mv; yo.z *= mv; yo.w *= mv;
        *(float4*)(Ys + r * YS_STRIDE + q * 4) = yo;
        __syncthreads();   // As + Ys ready

        // ---- U += A^T @ Y: thread owns k=lane, cols wave*4..+3 ----
        for (int l = 0; l < 64; ++l) {
            float av = As[l * 64 + lane];                                // conflict-free
            float4 yv = *(const float4*)(Ys + l * YS_STRIDE + wave * 4); // bcast
            accU[0] += av * yv.x; accU[1] += av * yv.y;
            accU[2] += av * yv.z; accU[3] += av * yv.w;
        }
        __syncthreads();   // protect As/Ys for next tile
    }

    float4 uo = {accU[0], accU[1], accU[2], accU[3]};
    *(float4*)(Part + ((long)(c * 64 + b)) * 1024 + lane * 16 + wave * 4) = uo;
}

// ---------------- Kernel 2a: z = (sum_c Part) @ Hc (f32) ------------------
__global__ __launch_bounds__(256) void k2a_z(
    const float* __restrict__ Part,         // [16][64][1024]
    const float* __restrict__ Hc,           // [1024,512]
    float* __restrict__ zws)                // [64,512]
{
    __shared__ __align__(16) float Us[4 * 1024];

    const int tid = threadIdx.x;
    const int mt  = blockIdx.x >> 3;        // 16 row-groups of 4
    const int nt  = blockIdx.x & 7;         // 8 col-groups of 64

#pragma unroll
    for (int i = 0; i < 16; ++i) {
        int flat = i * 256 + tid;
        int brow = flat >> 10;
        int col  = flat & 1023;
        float s = 0.f;
#pragma unroll
        for (int cc = 0; cc < 16; ++cc)
            s += Part[((long)(cc * 64 + mt * 4 + brow)) * 1024 + col];
        Us[flat] = s;
    }
    __syncthreads();

    const int r  = tid >> 6;
    const int cg = nt * 64 + (tid & 63);
    const float* ur = Us + r * 1024;
    float acc = 0.f;
    for (int k = 0; k < 1024; k += 4) {
        float4 uv = *(const float4*)(ur + k);
        acc += uv.x * Hc[(k + 0) * 512 + cg];
        acc += uv.y * Hc[(k + 1) * 512 + cg];
        acc += uv.z * Hc[(k + 2) * 512 + cg];
        acc += uv.w * Hc[(k + 3) * 512 + cg];
    }
    zws[((long)mt * 4 + r) * 512 + cg] = acc;
}

// ---------------- Kernel 2b: expander head (f32 -> f32) -------------------
__global__ __launch_bounds__(256) void k2b_head(
    const float* __restrict__ zws,          // [64,512]
    const float* __restrict__ W1,           // [512,512]
    const float* __restrict__ b1,
    const float* __restrict__ lnw,
    const float* __restrict__ lnb,
    const float* __restrict__ W2,
    const float* __restrict__ b2,
    float* __restrict__ out)                // [64,512] f32
{
    __shared__ __align__(16) float zs[512];
    __shared__ __align__(16) float hs[512];
    __shared__ float red[8];

    const int tid  = threadIdx.x;
    const int lane = tid & 63;
    const int wave = tid >> 6;
    const int b    = blockIdx.x;

    zs[tid] = zws[(long)b * 512 + tid];
    zs[tid + 256] = zws[(long)b * 512 + tid + 256];
    __syncthreads();

    float h0 = b1[tid], h1 = b1[tid + 256];
    for (int k = 0; k < 512; k += 4) {
        float4 zv = *(const float4*)(zs + k);
        h0 += zv.x * W1[(k + 0) * 512 + tid];
        h0 += zv.y * W1[(k + 1) * 512 + tid];
        h0 += zv.z * W1[(k + 2) * 512 + tid];
        h0 += zv.w * W1[(k + 3) * 512 + tid];
        h1 += zv.x * W1[(k + 0) * 512 + tid + 256];
        h1 += zv.y * W1[(k + 1) * 512 + tid + 256];
        h1 += zv.z * W1[(k + 2) * 512 + tid + 256];
        h1 += zv.w * W1[(k + 3) * 512 + tid + 256];
    }

    float s = h0 + h1, s2 = h0 * h0 + h1 * h1;
#pragma unroll
    for (int m = 32; m >= 1; m >>= 1) {
        s  += __shfl_xor(s, m);
        s2 += __shfl_xor(s2, m);
    }
    if (lane == 0) { red[wave] = s; red[wave + 4] = s2; }
    __syncthreads();
    float ts  = red[0] + red[1] + red[2] + red[3];
    float ts2 = red[4] + red[5] + red[6] + red[7];
    float mu   = ts * (1.f / 512.f);
    float var  = ts2 * (1.f / 512.f) - mu * mu;
    float rstd = rsqrtf(var + 1e-5f);

    float g0 = (h0 - mu) * rstd * lnw[tid] + lnb[tid];
    float g1 = (h1 - mu) * rstd * lnw[tid + 256] + lnb[tid + 256];
    hs[tid] = g0 > 0.f ? g0 : 0.f;
    hs[tid + 256] = g1 > 0.f ? g1 : 0.f;
    __syncthreads();

    float o0 = b2[tid], o1 = b2[tid + 256];
    for (int k = 0; k < 512; k += 4) {
        float4 hv = *(const float4*)(hs + k);
        o0 += hv.x * W2[(k + 0) * 512 + tid];
        o0 += hv.y * W2[(k + 1) * 512 + tid];
        o0 += hv.z * W2[(k + 2) * 512 + tid];
        o0 += hv.w * W2[(k + 3) * 512 + tid];
        o1 += hv.x * W2[(k + 0) * 512 + tid + 256];
        o1 += hv.y * W2[(k + 1) * 512 + tid + 256];
        o1 += hv.z * W2[(k + 2) * 512 + tid + 256];
        o1 += hv.w * W2[(k + 3) * 512 + tid + 256];
    }
    out[(long)b * 512 + tid] = o0;
    out[(long)b * 512 + tid + 256] = o1;
}

extern "C" void kernel_launch(void* const* d_in, const int* in_sizes, int n_in,
                              void* d_out, int out_size, void* d_ws, size_t ws_size,
                              hipStream_t stream) {
    const float* emb = (const float*)d_in[0];
    const void*  msk = (const void*)d_in[1];
    const float* Bc  = (const float*)d_in[2];
    const float* Ac  = (const float*)d_in[3];
    const float* Hc  = (const float*)d_in[4];
    const float* W1  = (const float*)d_in[5];
    const float* b1  = (const float*)d_in[6];
    const float* lnw = (const float*)d_in[7];
    const float* lnb = (const float*)d_in[8];
    const float* W2  = (const float*)d_in[9];
    const float* b2  = (const float*)d_in[10];

    float* Part = (float*)d_ws;                               // 4 MB
    float* zws  = (float*)((char*)d_ws + 16 * 64 * 1024 * 4); // 128 KB
    int*   flg  = (int*)((char*)d_ws + 16 * 64 * 1024 * 4 + 64 * 512 * 4);

    hipMemsetAsync(flg, 0, 4, stream);
    detect_mask<<<64, 256, 0, stream>>>((const unsigned int*)msk, flg);
    k1_proj<<<1024, 256, 0, stream>>>(emb, msk, Bc, Ac, Part, flg);
    k2a_z<<<128, 256, 0, stream>>>(Part, Hc, zws);
    k2b_head<<<64, 256, 0, stream>>>(zws, W1, b1, lnw, lnb, W2, b2,
                                     (float*)d_out);
}

// Round 7
// 288.921 us; speedup vs baseline: 3.4492x; 1.1621x over previous
//
#include <hip/hip_runtime.h>

// ESMProjectionHead — f32 in, f32 out. B=64, L=4096, D=128, RL=64, RD=16, DOUT=512
// R7: k1 = R6 structure + BcS bank-swizzle (chunk q at +4-bank offset) -> conflict-free.
//     k2_fused = one block per batch row: U-reduce -> z=U@Hc -> h=z@W1+b1 -> LN/ReLU
//     -> out=h@W2+b2, K split across wave-pairs, float4 weight loads, LDS partials.

// ---------------- mask-layout detection -----------------------------------
__global__ __launch_bounds__(256) void detect_mask(
    const unsigned int* __restrict__ m, int* __restrict__ flag)
{
    unsigned int v = 0;
    int base = (blockIdx.x * 256 + threadIdx.x) * 4;
#pragma unroll
    for (int i = 0; i < 4; ++i) v |= m[base + i];
    unsigned long long any = __ballot(v > 1u);
    if ((threadIdx.x & 63) == 0 && any) atomicOr(flag, 1);
}

// ---------------- Kernel 1: low-rank projections (f32) --------------------
#define YS_STRIDE 20
#define BCS_CHUNK 516   // 32 ks * 16 cols + 4 pad: chunk q starts at bank 4q
__global__ __launch_bounds__(256, 4) void k1_proj(
    const float* __restrict__ emb,          // [64,4096,128]
    const void* __restrict__ maskp,         // [64,4096] bool (byte or int32)
    const float* __restrict__ Bc,           // [128,16]
    const float* __restrict__ Ac,           // [4096,64]
    float* __restrict__ Part,               // [16][64][1024] f32 partials
    const int* __restrict__ flag)
{
    __shared__ __align__(16) float BcS[4 * BCS_CHUNK];  // 8.1 KB swizzled
    __shared__ __align__(16) float As[64 * 64];         // 16 KB
    __shared__ __align__(16) float Ys[64 * YS_STRIDE];  // 5.1 KB

    const int tid  = threadIdx.x;
    const int lane = tid & 63;
    const int wave = tid >> 6;
    const int q    = tid & 3;               // K-quarter (32 ks)
    const int r    = tid >> 2;              // row within 64-row sub-tile
    const int b    = blockIdx.x >> 4;
    const int c    = blockIdx.x & 15;       // 256-row chunk
    const int byte_mode = *flag;            // block-uniform

    // stage Bc once, swizzled: element (k,col) -> (k>>5)*BCS_CHUNK + (k&31)*16 + col
#pragma unroll
    for (int i = 0; i < 8; ++i) {
        int e = i * 256 + tid;              // [0,2048)
        int k = e >> 4, col = e & 15;
        BcS[(k >> 5) * BCS_CHUNK + (k & 31) * 16 + col] = Bc[e];
    }
    __syncthreads();

    float accU[4] = {0.f, 0.f, 0.f, 0.f};   // U[k=lane][wave*4 .. +3]

    for (int t = 0; t < 4; ++t) {
        const long l0 = (long)c * 256 + t * 64;
        const float* asrc = Ac + l0 * 64;

        // stage A tile 64x64 (16 KB): 4 x float4 per thread
#pragma unroll
        for (int i = 0; i < 4; ++i) {
            int e = (i * 256 + tid) * 4;
            *(float4*)(As + e) = *(const float4*)(asrc + e);
        }

        // ---- X straight to registers: row r, ks q*32..q*32+31 ----
        const float* xrow = emb + ((long)b * 4096 + l0 + r) * 128 + q * 32;
        float4 xv[8];
#pragma unroll
        for (int j = 0; j < 8; ++j) xv[j] = *(const float4*)(xrow + j * 4);

        // ---- y[16] = sum over this thread's 32 ks of x[k]*Bc[k][:] ----
        const float* bq = BcS + q * BCS_CHUNK;   // conflict-free across q now
        float y[16];
#pragma unroll
        for (int j = 0; j < 16; ++j) y[j] = 0.f;
#pragma unroll
        for (int j4 = 0; j4 < 8; ++j4) {
            float4 v = xv[j4];
#pragma unroll
            for (int i = 0; i < 4; ++i) {
                int kk = j4 * 4 + i;        // k within chunk
                float x = (i == 0) ? v.x : (i == 1) ? v.y : (i == 2) ? v.z : v.w;
#pragma unroll
                for (int c4 = 0; c4 < 4; ++c4) {
                    float4 bv = *(const float4*)(bq + kk * 16 + c4 * 4);
                    y[c4 * 4 + 0] += x * bv.x;
                    y[c4 * 4 + 1] += x * bv.y;
                    y[c4 * 4 + 2] += x * bv.z;
                    y[c4 * 4 + 3] += x * bv.w;
                }
            }
        }
        // reduce the 4 K-quarters (register-only)
#pragma unroll
        for (int j = 0; j < 16; ++j) {
            y[j] += __shfl_xor(y[j], 1);
            y[j] += __shfl_xor(y[j], 2);
        }

        long midx = (long)b * 4096 + l0 + r;
        bool mb = byte_mode ? (((const unsigned char*)maskp)[midx] != 0)
                            : (((const int*)maskp)[midx] != 0);
        float mv = mb ? 1.f : 0.f;
        float4 yo;
        if (q == 0)      yo = make_float4(y[0],  y[1],  y[2],  y[3]);
        else if (q == 1) yo = make_float4(y[4],  y[5],  y[6],  y[7]);
        else if (q == 2) yo = make_float4(y[8],  y[9],  y[10], y[11]);
        else             yo = make_float4(y[12], y[13], y[14], y[15]);
        yo.x *= mv; yo.y *= mv; yo.z *= mv; yo.w *= mv;
        *(float4*)(Ys + r * YS_STRIDE + q * 4) = yo;
        __syncthreads();

        // ---- U += A^T @ Y: thread owns k=lane, cols wave*4..+3 ----
        for (int l = 0; l < 64; ++l) {
            float av = As[l * 64 + lane];                                // conflict-free
            float4 yv = *(const float4*)(Ys + l * YS_STRIDE + wave * 4); // bcast
            accU[0] += av * yv.x; accU[1] += av * yv.y;
            accU[2] += av * yv.z; accU[3] += av * yv.w;
        }
        __syncthreads();
    }

    float4 uo = {accU[0], accU[1], accU[2], accU[3]};
    *(float4*)(Part + ((long)(c * 64 + b)) * 1024 + lane * 16 + wave * 4) = uo;
}

// ---------------- Kernel 2 (fused): U-reduce -> z -> h -> LN -> out -------
__global__ __launch_bounds__(512) void k2_fused(
    const float* __restrict__ Part,         // [16][64][1024]
    const float* __restrict__ Hc,           // [1024,512]
    const float* __restrict__ W1,           // [512,512]
    const float* __restrict__ b1,
    const float* __restrict__ lnw,
    const float* __restrict__ lnb,
    const float* __restrict__ W2,           // [512,512]
    const float* __restrict__ b2,
    float* __restrict__ out)                // [64,512]
{
    __shared__ __align__(16) float Us[1024];     // 4 KB
    __shared__ __align__(16) float zs[512];      // 2 KB
    __shared__ __align__(16) float hs[512];      // 2 KB
    __shared__ __align__(16) float hp4[4][512];  // 8 KB partials
    __shared__ float red[16];

    const int tid  = threadIdx.x;           // 512 threads
    const int lane = tid & 63;
    const int wave = tid >> 6;              // 8 waves
    const int kq   = wave >> 1;             // wave-pair id 0..3 (K-split)
    const int c4   = (tid & 127) * 4;       // 4 consecutive output cols
    const int b    = blockIdx.x;

    // ---- Phase A: Us = sum_cc Part[cc][b][:]  (thread owns 2 cols) ----
    {
        const float* pb = Part + (long)b * 1024 + tid * 2;
        float2 s = {0.f, 0.f};
#pragma unroll
        for (int cc = 0; cc < 16; ++cc) {
            float2 v = *(const float2*)(pb + (long)cc * 64 * 1024);
            s.x += v.x; s.y += v.y;
        }
        *(float2*)(Us + tid * 2) = s;
    }
    __syncthreads();

    // ---- Phase B: z = Us @ Hc  (K=1024 split in 4 x 256) ----
    {
        float a0 = 0.f, a1 = 0.f, a2 = 0.f, a3 = 0.f;
        const int k0 = kq * 256;
        for (int k4 = 0; k4 < 256; k4 += 4) {
            float4 u = *(const float4*)(Us + k0 + k4);    // wave-uniform bcast
            const float* hcp = Hc + (long)(k0 + k4) * 512 + c4;
            float4 w0 = *(const float4*)(hcp);
            float4 w1v = *(const float4*)(hcp + 512);
            float4 w2v = *(const float4*)(hcp + 1024);
            float4 w3 = *(const float4*)(hcp + 1536);
            a0 += u.x * w0.x + u.y * w1v.x + u.z * w2v.x + u.w * w3.x;
            a1 += u.x * w0.y + u.y * w1v.y + u.z * w2v.y + u.w * w3.y;
            a2 += u.x * w0.z + u.y * w1v.z + u.z * w2v.z + u.w * w3.z;
            a3 += u.x * w0.w + u.y * w1v.w + u.z * w2v.w + u.w * w3.w;
        }
        float4 p = {a0, a1, a2, a3};
        *(float4*)(&hp4[kq][c4]) = p;
    }
    __syncthreads();
    if (tid < 512) {   // all threads: reduce 4 partials for col=tid
        zs[tid] = hp4[0][tid] + hp4[1][tid] + hp4[2][tid] + hp4[3][tid];
    }
    __syncthreads();

    // ---- Phase C: h = zs @ W1 + b1 (K=512 split in 4 x 128), then LN+ReLU ----
    {
        float a0 = 0.f, a1 = 0.f, a2 = 0.f, a3 = 0.f;
        const int k0 = kq * 128;
        for (int k4 = 0; k4 < 128; k4 += 4) {
            float4 u = *(const float4*)(zs + k0 + k4);
            const float* wp = W1 + (long)(k0 + k4) * 512 + c4;
            float4 w0 = *(const float4*)(wp);
            float4 w1v = *(const float4*)(wp + 512);
            float4 w2v = *(const float4*)(wp + 1024);
            float4 w3 = *(const float4*)(wp + 1536);
            a0 += u.x * w0.x + u.y * w1v.x + u.z * w2v.x + u.w * w3.x;
            a1 += u.x * w0.y + u.y * w1v.y + u.z * w2v.y + u.w * w3.y;
            a2 += u.x * w0.z + u.y * w1v.z + u.z * w2v.z + u.w * w3.z;
            a3 += u.x * w0.w + u.y * w1v.w + u.z * w2v.w + u.w * w3.w;
        }
        float4 p = {a0, a1, a2, a3};
        *(float4*)(&hp4[kq][c4]) = p;
    }
    __syncthreads();

    float hv = hp4[0][tid] + hp4[1][tid] + hp4[2][tid] + hp4[3][tid] + b1[tid];
    // block-wide LN stats over 512 cols
    float s = hv, s2 = hv * hv;
#pragma unroll
    for (int m = 32; m >= 1; m >>= 1) {
        s  += __shfl_xor(s, m);
        s2 += __shfl_xor(s2, m);
    }
    if (lane == 0) { red[wave] = s; red[wave + 8] = s2; }
    __syncthreads();
    float ts = 0.f, ts2 = 0.f;
#pragma unroll
    for (int i = 0; i < 8; ++i) { ts += red[i]; ts2 += red[i + 8]; }
    float mu   = ts * (1.f / 512.f);
    float var  = ts2 * (1.f / 512.f) - mu * mu;
    float rstd = rsqrtf(var + 1e-5f);
    float g = (hv - mu) * rstd * lnw[tid] + lnb[tid];
    hs[tid] = g > 0.f ? g : 0.f;
    __syncthreads();

    // ---- Phase D: out = hs @ W2 + b2 ----
    {
        float a0 = 0.f, a1 = 0.f, a2 = 0.f, a3 = 0.f;
        const int k0 = kq * 128;
        for (int k4 = 0; k4 < 128; k4 += 4) {
            float4 u = *(const float4*)(hs + k0 + k4);
            const float* wp = W2 + (long)(k0 + k4) * 512 + c4;
            float4 w0 = *(const float4*)(wp);
            float4 w1v = *(const float4*)(wp + 512);
            float4 w2v = *(const float4*)(wp + 1024);
            float4 w3 = *(const float4*)(wp + 1536);
            a0 += u.x * w0.x + u.y * w1v.x + u.z * w2v.x + u.w * w3.x;
            a1 += u.x * w0.y + u.y * w1v.y + u.z * w2v.y + u.w * w3.y;
            a2 += u.x * w0.z + u.y * w1v.z + u.z * w2v.z + u.w * w3.z;
            a3 += u.x * w0.w + u.y * w1v.w + u.z * w2v.w + u.w * w3.w;
        }
        float4 p = {a0, a1, a2, a3};
        *(float4*)(&hp4[kq][c4]) = p;
    }
    __syncthreads();
    out[(long)b * 512 + tid] = hp4[0][tid] + hp4[1][tid] + hp4[2][tid]
                             + hp4[3][tid] + b2[tid];
}

extern "C" void kernel_launch(void* const* d_in, const int* in_sizes, int n_in,
                              void* d_out, int out_size, void* d_ws, size_t ws_size,
                              hipStream_t stream) {
    const float* emb = (const float*)d_in[0];
    const void*  msk = (const void*)d_in[1];
    const float* Bc  = (const float*)d_in[2];
    const float* Ac  = (const float*)d_in[3];
    const float* Hc  = (const float*)d_in[4];
    const float* W1  = (const float*)d_in[5];
    const float* b1  = (const float*)d_in[6];
    const float* lnw = (const float*)d_in[7];
    const float* lnb = (const float*)d_in[8];
    const float* W2  = (const float*)d_in[9];
    const float* b2  = (const float*)d_in[10];

    float* Part = (float*)d_ws;                               // 4 MB
    int*   flg  = (int*)((char*)d_ws + 16 * 64 * 1024 * 4);

    hipMemsetAsync(flg, 0, 4, stream);
    detect_mask<<<64, 256, 0, stream>>>((const unsigned int*)msk, flg);
    k1_proj<<<1024, 256, 0, stream>>>(emb, msk, Bc, Ac, Part, flg);
    k2_fused<<<64, 512, 0, stream>>>(Part, Hc, W1, b1, lnw, lnb, W2, b2,
                                     (float*)d_out);
}